// Round 4
// baseline (1272.081 us; speedup 1.0000x reference)
//
#include <hip/hip_runtime.h>

// Problem dims
#define TT 512
#define BB 64
#define DXX 128
#define HH 256
#define DZZ 64

typedef __attribute__((ext_vector_type(8))) short short8;
typedef __attribute__((ext_vector_type(4))) float f32x4;

#define DEV static __device__ __forceinline__

DEV unsigned short f2bf(float f){
  unsigned u = __builtin_bit_cast(unsigned, f);
  u += 0x7FFFu + ((u >> 16) & 1u);          // RNE
  return (unsigned short)(u >> 16);
}
DEV unsigned pack2(float lo, float hi){     // 2 f32 -> packed bf16x2 (proven path)
  return (unsigned)f2bf(lo) | ((unsigned)f2bf(hi) << 16);
}
DEV float bfLO(unsigned u){ return __builtin_bit_cast(float, u << 16); }
DEV float bfHI(unsigned u){ return __builtin_bit_cast(float, u & 0xffff0000u); }
DEV float ftanh(float x){                   // round-2 proven form
  float a = fabsf(x);
  float e = __expf(-2.f * a);
  float r = __builtin_amdgcn_rcpf(1.f + e);
  float t = (1.f - e) * r;
  return copysignf(t, x);
}
DEV float fsoftplus(float x){
  float e = __expf(fminf(x, 20.f));
  float s = __logf(1.f + e);
  return (x > 20.f) ? x : s;
}
DEV short8 pack8(const float* p){           // 8 consecutive f32 -> bf16x8
  short8 v;
  #pragma unroll
  for (int i = 0; i < 8; ++i) v[i] = (short)f2bf(p[i]);
  return v;
}

// Fragment conventions (m89-verified, mfma_f32_16x16x32_bf16), SWAPPED use:
//   D = A*B with A = weight tile (16 out-cols x K), B = h^T (K x 16 batch).
//   A-frag: lane l elem e: W[outcol_local = l&15][k = (l>>4)*8 + e]
//   B-frag: lane l elem e: h[batch = l&15][k = (l>>4)*8 + e]
//   C/D:    lane l reg r:  value(batch = l&15, outcol = tile + 4*(l>>4) + r)
// Lane payload (per wave q, lane l): 16 bf16 = 8 words; word wi = ni*2 + rp:
//   lo = value(ni, 2rp), hi = value(ni, 2rp+1); outcol n = 64q+16ni+4*(l>>4)+reg.

// ---------------------------------------------------------------------------
// Phase A: xp = X @ Wih^T + bih + bhh (both dirs), stored bf16 lane-packed:
// xpF[d][s][bq][q][l][16]
// ---------------------------------------------------------------------------
__global__ __launch_bounds__(256, 2) void phaseA(
    const float* __restrict__ X,
    const float* __restrict__ WihF, const float* __restrict__ bihF, const float* __restrict__ bhhF,
    const float* __restrict__ WihB, const float* __restrict__ bihB, const float* __restrict__ bhhB,
    unsigned short* __restrict__ xpF)
{
  const int bid = blockIdx.x;
  const int d = bid >> 9, s = bid & 511;
  const int ts = d ? (TT - 1 - s) : s;
  const float* W  = d ? WihB : WihF;
  const float* bi = d ? bihB : bihF;
  const float* bh = d ? bhhB : bhhF;

  const int tid = threadIdx.x, q = tid >> 6, l = tid & 63;
  const int l15 = l & 15, l4 = l >> 4;

  short8 wf[4][4];
  f32x4 bias[4];
  #pragma unroll
  for (int ni = 0; ni < 4; ++ni){
    int n = 64*q + 16*ni + l15;
    #pragma unroll
    for (int ks = 0; ks < 4; ++ks)
      wf[ni][ks] = pack8(W + (size_t)n * DXX + ks*32 + l4*8);
    int n0 = 64*q + 16*ni + 4*l4;
    float4 b1 = *(const float4*)(bi + n0);
    float4 b2 = *(const float4*)(bh + n0);
    bias[ni][0]=b1.x+b2.x; bias[ni][1]=b1.y+b2.y; bias[ni][2]=b1.z+b2.z; bias[ni][3]=b1.w+b2.w;
  }

  #pragma unroll
  for (int bq = 0; bq < 4; ++bq){
    const float* xr = X + ((size_t)ts * 64 + 16*bq + l15) * DXX;
    short8 xf[4];
    #pragma unroll
    for (int ks = 0; ks < 4; ++ks) xf[ks] = pack8(xr + ks*32 + l4*8);

    f32x4 acc[4];
    #pragma unroll
    for (int ni = 0; ni < 4; ++ni) acc[ni] = bias[ni];
    #pragma unroll
    for (int ks = 0; ks < 4; ++ks)
      #pragma unroll
      for (int ni = 0; ni < 4; ++ni)
        acc[ni] = __builtin_amdgcn_mfma_f32_16x16x32_bf16(wf[ni][ks], xf[ks], acc[ni], 0, 0, 0);

    unsigned wd[8];
    #pragma unroll
    for (int ni = 0; ni < 4; ++ni){
      wd[ni*2]   = pack2(acc[ni][0], acc[ni][1]);
      wd[ni*2+1] = pack2(acc[ni][2], acc[ni][3]);
    }
    unsigned short* dst = xpF + ((((size_t)d*TT + s)*4 + bq)*4 + q)*1024 + (size_t)l*16;
    uint4 o0 = {wd[0], wd[1], wd[2], wd[3]};
    uint4 o1 = {wd[4], wd[5], wd[6], wd[7]};
    ((uint4*)dst)[0] = o0;
    ((uint4*)dst)[1] = o1;
  }
}

// ---------------------------------------------------------------------------
// Phase B: two RNN scans, 8 blocks (dir,bq) x 256 thr (4 waves).
// Whh in regs as A-frags; h in double-buffered swizzled LDS; 1 barrier/step.
// ---------------------------------------------------------------------------
__global__ __launch_bounds__(256, 1) void phaseB(
    const float* __restrict__ WhhF, const float* __restrict__ WhhB,
    const unsigned short* __restrict__ xpF, unsigned short* __restrict__ hF)
{
  const int dir = blockIdx.x >> 2, bq = blockIdx.x & 3;
  const float* Whh = dir ? WhhB : WhhF;
  const int tid = threadIdx.x, q = tid >> 6, l = tid & 63;
  const int l15 = l & 15, l4 = l >> 4;
  const int swz = (l15 & 7) << 3;
  const int rbase = l15 * 256;

  __shared__ __attribute__((aligned(16))) unsigned short hbuf[2][4096];

  short8 wf[4][8];
  #pragma unroll
  for (int ni = 0; ni < 4; ++ni){
    int n = 64*q + 16*ni + l15;
    #pragma unroll
    for (int ks = 0; ks < 8; ++ks)
      wf[ni][ks] = pack8(Whh + (size_t)n * HH + ks*32 + l4*8);
  }
  for (int i = tid; i < 2048; i += 256) ((unsigned*)hbuf[0])[i] = 0u;  // h_0 = 0

  const size_t strideS = 16384;   // ushorts per timestep
  const size_t laneOff = (size_t)bq*4096 + (size_t)q*1024 + (size_t)l*16;
  const unsigned short* xpP = xpF + (size_t)dir*TT*strideS + laneOff;
  unsigned short* hD = hF + (size_t)dir*TT*strideS + laneOff;

  uint4 xq0, xq1;
  { const uint4* src = (const uint4*)xpP; xq0 = src[0]; xq1 = src[1]; }

  uint4 p0, p1;
  size_t prevOff = 0;
  __syncthreads();

  for (int s = 0; s < TT; ++s){
    // deferred global store of h_{s-1}
    if (s > 0){
      *(uint4*)(hD + prevOff)     = p0;
      *(uint4*)(hD + prevOff + 8) = p1;
    }
    // prefetch next xp EARLY (unconditional, clamped in-bounds)
    uint4 xn0, xn1;
    {
      int sn = (s + 1 < TT) ? s + 1 : s;
      const uint4* src = (const uint4*)(xpP + (size_t)sn * strideS);
      xn0 = src[0]; xn1 = src[1];
    }
    // acc <- xp
    f32x4 acc[4];
    {
      unsigned W8[8] = {xq0.x, xq0.y, xq0.z, xq0.w, xq1.x, xq1.y, xq1.z, xq1.w};
      #pragma unroll
      for (int ni = 0; ni < 4; ++ni){
        acc[ni][0] = bfLO(W8[ni*2]);   acc[ni][1] = bfHI(W8[ni*2]);
        acc[ni][2] = bfLO(W8[ni*2+1]); acc[ni][3] = bfHI(W8[ni*2+1]);
      }
    }
    // W_hh * h_{s-1}^T
    const unsigned short* hb = hbuf[s & 1];
    #pragma unroll
    for (int ks = 0; ks < 8; ++ks){
      short8 b = *(const short8*)(hb + ((rbase + ks*32 + l4*8) ^ swz));
      #pragma unroll
      for (int ni = 0; ni < 4; ++ni)
        acc[ni] = __builtin_amdgcn_mfma_f32_16x16x32_bf16(wf[ni][ks], b, acc[ni], 0, 0, 0);
    }
    // tanh -> LDS (b64 packed) + pack for deferred global store
    unsigned short* hw = hbuf[(s & 1) ^ 1];
    unsigned wd[8];
    #pragma unroll
    for (int ni = 0; ni < 4; ++ni){
      float t0 = ftanh(acc[ni][0]), t1 = ftanh(acc[ni][1]);
      float t2 = ftanh(acc[ni][2]), t3 = ftanh(acc[ni][3]);
      unsigned lo = pack2(t0, t1), hi = pack2(t2, t3);
      wd[ni*2] = lo; wd[ni*2+1] = hi;
      int ea = rbase + ((64*q + 16*ni + 4*l4) ^ swz);
      uint2 v; v.x = lo; v.y = hi;
      *(uint2*)(hw + ea) = v;
    }
    p0.x=wd[0]; p0.y=wd[1]; p0.z=wd[2]; p0.w=wd[3];
    p1.x=wd[4]; p1.y=wd[5]; p1.z=wd[6]; p1.w=wd[7];
    prevOff = (size_t)(dir ? (TT - 1 - s) : s) * strideS;
    xq0 = xn0; xq1 = xn1;
    __syncthreads();
  }
  *(uint4*)(hD + prevOff)     = p0;
  *(uint4*)(hD + prevOff + 8) = p1;
}

// ---------------------------------------------------------------------------
// Phase C: latent scan, 4 blocks (bq) x 256 thr (4 waves), 2 barriers/step.
// Wave q owns out-cols [16q,16q+16) of mu AND sig -> z fully in-register.
// eps is loaded directly from the raw [T][B][DZ] array (float4 per lane).
// ---------------------------------------------------------------------------
__global__ __launch_bounds__(256, 1) void phaseC(
    const float* __restrict__ Wt,  const float* __restrict__ bt,
    const float* __restrict__ Wmu, const float* __restrict__ bmu,
    const float* __restrict__ Wsig,const float* __restrict__ bsig,
    const float* __restrict__ eps, const unsigned short* __restrict__ hF,
    float* __restrict__ out)
{
  const int bq = blockIdx.x;
  const int tid = threadIdx.x, q = tid >> 6, l = tid & 63;
  const int l15 = l & 15, l4 = l >> 4;
  const int swz = (l15 & 7) << 3;
  const int rbase = l15 * 256;
  const int zrbase = l15 * 64;

  __shared__ __attribute__((aligned(16))) unsigned short zbuf[1024];   // 16 x 64
  __shared__ __attribute__((aligned(16))) unsigned short hbuf[4096];   // 16 x 256

  // transition: A-frags of Wt rows (out-cols of H), K = DZ = 64
  short8 wtf[4][2]; f32x4 btb[4];
  #pragma unroll
  for (int ni = 0; ni < 4; ++ni){
    int n = 64*q + 16*ni + l15;
    #pragma unroll
    for (int ks = 0; ks < 2; ++ks)
      wtf[ni][ks] = pack8(Wt + (size_t)n * DZZ + ks*32 + l4*8);
    float4 b4 = *(const float4*)(bt + 64*q + 16*ni + 4*l4);
    btb[ni][0]=b4.x; btb[ni][1]=b4.y; btb[ni][2]=b4.z; btb[ni][3]=b4.w;
  }
  // mu/sig: A-frags of Wmu/Wsig rows (this wave's 16 out-cols), K = H = 256
  short8 wm[8], wsg[8];
  {
    int r = 16*q + l15;
    #pragma unroll
    for (int ks = 0; ks < 8; ++ks){
      wm[ks]  = pack8(Wmu  + (size_t)r * HH + ks*32 + l4*8);
      wsg[ks] = pack8(Wsig + (size_t)r * HH + ks*32 + l4*8);
    }
  }
  f32x4 bm4, bs4;
  {
    float4 a = *(const float4*)(bmu  + 16*q + 4*l4);
    float4 b = *(const float4*)(bsig + 16*q + 4*l4);
    bm4[0]=a.x; bm4[1]=a.y; bm4[2]=a.z; bm4[3]=a.w;
    bs4[0]=b.x; bs4[1]=b.y; bs4[2]=b.z; bs4[3]=b.w;
  }
  for (int i = tid; i < 512; i += 256) ((unsigned*)zbuf)[i] = 0u;   // z_0 = 0

  const size_t strideS = 16384;
  const size_t laneOff = (size_t)bq*4096 + (size_t)q*1024 + (size_t)l*16;
  const unsigned short* hLp = hF + laneOff;
  const unsigned short* hRp = hLp + (size_t)TT * strideS;
  const float* eP = eps + ((size_t)(16*bq + l15)) * 64 + 16*q + 4*l4;  // + t*4096

  uint4 hl0, hl1, hr0, hr1; f32x4 ef;
  {
    const uint4* sl = (const uint4*)hLp;
    const uint4* sr = (const uint4*)hRp;
    hl0 = sl[0]; hl1 = sl[1]; hr0 = sr[0]; hr1 = sr[1];
    float4 e4 = *(const float4*)eP;
    ef[0]=e4.x; ef[1]=e4.y; ef[2]=e4.z; ef[3]=e4.w;
  }
  const size_t TBZ = (size_t)TT * 64 * 64;
  f32x4 dz, dmu, dsp;
  size_t obPrev = 0;
  __syncthreads();

  for (int t = 0; t < TT; ++t){
    // deferred float4 stores for t-1
    if (t > 0){
      *(float4*)(out + obPrev)         = *(float4*)&dz;
      *(float4*)(out + TBZ + obPrev)   = *(float4*)&dmu;
      *(float4*)(out + 2*TBZ + obPrev) = *(float4*)&dsp;
    }
    // prefetch t+1 inputs EARLY (unconditional, clamped in-bounds)
    uint4 nl0, nl1, nr0, nr1; f32x4 nef;
    {
      int tn = (t + 1 < TT) ? t + 1 : t;
      const uint4* sl = (const uint4*)(hLp + (size_t)tn*strideS);
      const uint4* sr = (const uint4*)(hRp + (size_t)tn*strideS);
      nl0 = sl[0]; nl1 = sl[1]; nr0 = sr[0]; nr1 = sr[1];
      float4 e4 = *(const float4*)(eP + (size_t)tn*4096);
      nef[0]=e4.x; nef[1]=e4.y; nef[2]=e4.z; nef[3]=e4.w;
    }
    // 1) transition: Wt * z_prev^T + bt
    f32x4 at[4];
    #pragma unroll
    for (int ni = 0; ni < 4; ++ni) at[ni] = btb[ni];
    #pragma unroll
    for (int ks = 0; ks < 2; ++ks){
      short8 b = *(const short8*)(zbuf + ((zrbase + ks*32 + l4*8) ^ swz));
      #pragma unroll
      for (int ni = 0; ni < 4; ++ni)
        at[ni] = __builtin_amdgcn_mfma_f32_16x16x32_bf16(wtf[ni][ks], b, at[ni], 0, 0, 0);
    }
    // 2) h_t = (tanh(at) + hl + hr)/3 -> swizzled LDS (b64 packed)
    {
      unsigned HL[8] = {hl0.x, hl0.y, hl0.z, hl0.w, hl1.x, hl1.y, hl1.z, hl1.w};
      unsigned HR[8] = {hr0.x, hr0.y, hr0.z, hr0.w, hr1.x, hr1.y, hr1.z, hr1.w};
      #pragma unroll
      for (int ni = 0; ni < 4; ++ni){
        unsigned wl0 = HL[ni*2], wl1 = HL[ni*2+1];
        unsigned wr0 = HR[ni*2], wr1 = HR[ni*2+1];
        float h0 = (ftanh(at[ni][0]) + bfLO(wl0) + bfLO(wr0)) * (1.f/3.f);
        float h1 = (ftanh(at[ni][1]) + bfHI(wl0) + bfHI(wr0)) * (1.f/3.f);
        float h2 = (ftanh(at[ni][2]) + bfLO(wl1) + bfLO(wr1)) * (1.f/3.f);
        float h3 = (ftanh(at[ni][3]) + bfHI(wl1) + bfHI(wr1)) * (1.f/3.f);
        int ea = rbase + ((64*q + 16*ni + 4*l4) ^ swz);
        uint2 v; v.x = pack2(h0, h1); v.y = pack2(h2, h3);
        *(uint2*)(hbuf + ea) = v;
      }
    }
    __syncthreads();   // B1: h_t visible

    // 3) mu/sig (split accumulation chains 2x4)
    f32x4 a0 = bm4, s0 = bs4;
    f32x4 a1 = {0.f,0.f,0.f,0.f}, s1 = {0.f,0.f,0.f,0.f};
    #pragma unroll
    for (int ks = 0; ks < 4; ++ks){
      short8 b = *(const short8*)(hbuf + ((rbase + ks*32 + l4*8) ^ swz));
      a0 = __builtin_amdgcn_mfma_f32_16x16x32_bf16(wm[ks],  b, a0, 0, 0, 0);
      s0 = __builtin_amdgcn_mfma_f32_16x16x32_bf16(wsg[ks], b, s0, 0, 0, 0);
    }
    #pragma unroll
    for (int ks = 4; ks < 8; ++ks){
      short8 b = *(const short8*)(hbuf + ((rbase + ks*32 + l4*8) ^ swz));
      a1 = __builtin_amdgcn_mfma_f32_16x16x32_bf16(wm[ks],  b, a1, 0, 0, 0);
      s1 = __builtin_amdgcn_mfma_f32_16x16x32_bf16(wsg[ks], b, s1, 0, 0, 0);
    }
    f32x4 mu = a0 + a1;
    f32x4 sg = s0 + s1;
    // 4) reparameterization in-register; z -> swizzled LDS (b64)
    #pragma unroll
    for (int reg = 0; reg < 4; ++reg){
      float sp = fsoftplus(sg[reg]);
      float zv = __builtin_fmaf(sp, ef[reg], mu[reg]);
      dz[reg] = zv; dmu[reg] = mu[reg]; dsp[reg] = sp;
    }
    {
      int zea = zrbase + ((16*q + 4*l4) ^ swz);
      uint2 v; v.x = pack2(dz[0], dz[1]); v.y = pack2(dz[2], dz[3]);
      *(uint2*)(zbuf + zea) = v;
    }
    obPrev = ((size_t)t*64 + 16*bq + l15)*64 + 16*q + 4*l4;
    hl0 = nl0; hl1 = nl1; hr0 = nr0; hr1 = nr1; ef = nef;
    __syncthreads();   // B2: z_t visible for next transition
  }
  *(float4*)(out + obPrev)         = *(float4*)&dz;
  *(float4*)(out + TBZ + obPrev)   = *(float4*)&dmu;
  *(float4*)(out + 2*TBZ + obPrev) = *(float4*)&dsp;
}

// ---------------------------------------------------------------------------
extern "C" void kernel_launch(void* const* d_in, const int* in_sizes, int n_in,
                              void* d_out, int out_size, void* d_ws, size_t ws_size,
                              hipStream_t stream)
{
  const float* X      = (const float*)d_in[0];
  const float* Wih_f  = (const float*)d_in[1];
  const float* Whh_f  = (const float*)d_in[2];
  const float* bih_f  = (const float*)d_in[3];
  const float* bhh_f  = (const float*)d_in[4];
  const float* Wih_b  = (const float*)d_in[5];
  const float* Whh_b  = (const float*)d_in[6];
  const float* bih_b  = (const float*)d_in[7];
  const float* bhh_b  = (const float*)d_in[8];
  const float* Wt     = (const float*)d_in[9];
  const float* bt     = (const float*)d_in[10];
  const float* Wmu    = (const float*)d_in[11];
  const float* bmu    = (const float*)d_in[12];
  const float* Wsig   = (const float*)d_in[13];
  const float* bsig   = (const float*)d_in[14];
  const float* eps    = (const float*)d_in[15];

  // Workspace: xpF (33.5MB) + hF (33.5MB)
  unsigned short* xpF = (unsigned short*)d_ws;
  unsigned short* hF  = xpF + (size_t)2 * TT * 16384;

  phaseA<<<dim3(1024), dim3(256), 0, stream>>>(X, Wih_f, bih_f, bhh_f, Wih_b, bih_b, bhh_b, xpF);
  phaseB<<<dim3(8), dim3(256), 0, stream>>>(Whh_f, Whh_b, xpF, hF);
  phaseC<<<dim3(4), dim3(256), 0, stream>>>(Wt, bt, Wmu, bmu, Wsig, bsig, eps, hF, (float*)d_out);
}

// Round 5
// 1246.803 us; speedup vs baseline: 1.0203x; 1.0203x over previous
//
#include <hip/hip_runtime.h>

// Problem dims
#define TT 512
#define BB 64
#define DXX 128
#define HH 256
#define DZZ 64

typedef __attribute__((ext_vector_type(8))) short short8;
typedef __attribute__((ext_vector_type(4))) float f32x4;

#define DEV static __device__ __forceinline__
#define MFMA(a,b,c) __builtin_amdgcn_mfma_f32_16x16x32_bf16((a),(b),(c),0,0,0)

DEV unsigned short f2bf(float f){
  unsigned u = __builtin_bit_cast(unsigned, f);
  u += 0x7FFFu + ((u >> 16) & 1u);          // RNE
  return (unsigned short)(u >> 16);
}
DEV unsigned pack2(float lo, float hi){     // 2 f32 -> packed bf16x2
  return (unsigned)f2bf(lo) | ((unsigned)f2bf(hi) << 16);
}
DEV float bfLO(unsigned u){ return __builtin_bit_cast(float, u << 16); }
DEV float bfHI(unsigned u){ return __builtin_bit_cast(float, u & 0xffff0000u); }
DEV float ftanh(float x){
  float a = fabsf(x);
  float e = __expf(-2.f * a);
  float r = __builtin_amdgcn_rcpf(1.f + e);
  float t = (1.f - e) * r;
  return copysignf(t, x);
}
DEV float fsoftplus(float x){
  float e = __expf(fminf(x, 20.f));
  float s = __logf(1.f + e);
  return (x > 20.f) ? x : s;
}
DEV short8 pack8(const float* p){           // 8 consecutive f32 -> bf16x8
  short8 v;
  #pragma unroll
  for (int i = 0; i < 8; ++i) v[i] = (short)f2bf(p[i]);
  return v;
}
// LDS-only barrier: drains lgkmcnt but leaves global loads/stores in flight
// (T4: __syncthreads would emit s_waitcnt vmcnt(0) and kill the prefetches).
DEV void barrier_lgkm(){
  asm volatile("s_waitcnt lgkmcnt(0)" ::: "memory");
  __builtin_amdgcn_sched_barrier(0);
  __builtin_amdgcn_s_barrier();
  __builtin_amdgcn_sched_barrier(0);
}

// Fragment conventions (verified rounds 1-4, mfma_f32_16x16x32_bf16), swapped:
//   D = A*B, A = weight tile (16 out-cols x K), B = state^T (K x 16 batch).
//   A-frag: lane l elem e: W[outcol = l&15][k = (l>>4)*8 + e]
//   B-frag: lane l elem e: h[batch = l&15][k = (l>>4)*8 + e]
//   C/D:    lane l reg r:  value(batch = l&15, outcol = tile + 4*(l>>4) + r)

// ---------------------------------------------------------------------------
// Phase A: xp = X @ Wih^T + bih + bhh (both dirs), bf16 lane-packed:
// xpF[d][s][bq][q][l][16]
// ---------------------------------------------------------------------------
__global__ __launch_bounds__(256, 2) void phaseA(
    const float* __restrict__ X,
    const float* __restrict__ WihF, const float* __restrict__ bihF, const float* __restrict__ bhhF,
    const float* __restrict__ WihB, const float* __restrict__ bihB, const float* __restrict__ bhhB,
    unsigned short* __restrict__ xpF)
{
  const int bid = blockIdx.x;
  const int d = bid >> 9, s = bid & 511;
  const int ts = d ? (TT - 1 - s) : s;
  const float* W  = d ? WihB : WihF;
  const float* bi = d ? bihB : bihF;
  const float* bh = d ? bhhB : bhhF;

  const int tid = threadIdx.x, q = tid >> 6, l = tid & 63;
  const int l15 = l & 15, l4 = l >> 4;

  short8 wf[4][4];
  f32x4 bias[4];
  #pragma unroll
  for (int ni = 0; ni < 4; ++ni){
    int n = 64*q + 16*ni + l15;
    #pragma unroll
    for (int ks = 0; ks < 4; ++ks)
      wf[ni][ks] = pack8(W + (size_t)n * DXX + ks*32 + l4*8);
    int n0 = 64*q + 16*ni + 4*l4;
    float4 b1 = *(const float4*)(bi + n0);
    float4 b2 = *(const float4*)(bh + n0);
    bias[ni][0]=b1.x+b2.x; bias[ni][1]=b1.y+b2.y; bias[ni][2]=b1.z+b2.z; bias[ni][3]=b1.w+b2.w;
  }

  #pragma unroll
  for (int bq = 0; bq < 4; ++bq){
    const float* xr = X + ((size_t)ts * 64 + 16*bq + l15) * DXX;
    short8 xf[4];
    #pragma unroll
    for (int ks = 0; ks < 4; ++ks) xf[ks] = pack8(xr + ks*32 + l4*8);

    f32x4 acc[4];
    #pragma unroll
    for (int ni = 0; ni < 4; ++ni) acc[ni] = bias[ni];
    #pragma unroll
    for (int ks = 0; ks < 4; ++ks)
      #pragma unroll
      for (int ni = 0; ni < 4; ++ni)
        acc[ni] = MFMA(wf[ni][ks], xf[ks], acc[ni]);

    unsigned wd[8];
    #pragma unroll
    for (int ni = 0; ni < 4; ++ni){
      wd[ni*2]   = pack2(acc[ni][0], acc[ni][1]);
      wd[ni*2+1] = pack2(acc[ni][2], acc[ni][3]);
    }
    unsigned short* dst = xpF + ((((size_t)d*TT + s)*4 + bq)*4 + q)*1024 + (size_t)l*16;
    uint4 o0 = {wd[0], wd[1], wd[2], wd[3]};
    uint4 o1 = {wd[4], wd[5], wd[6], wd[7]};
    ((uint4*)dst)[0] = o0;
    ((uint4*)dst)[1] = o1;
  }
}

// ---------------------------------------------------------------------------
// Phase B: two RNN scans, 8 blocks (dir,bq) x 256 thr (4 waves).
// Whh in regs; h in double-buffered swizzled LDS; 1 LDS-only barrier/step;
// xp prefetched 2 steps ahead (manual unroll-2, no reg-copy).
// ---------------------------------------------------------------------------
__global__ __launch_bounds__(256, 1) void phaseB(
    const float* __restrict__ WhhF, const float* __restrict__ WhhB,
    const unsigned short* __restrict__ xpF, unsigned short* __restrict__ hF)
{
  const int dir = blockIdx.x >> 2, bq = blockIdx.x & 3;
  const float* Whh = dir ? WhhB : WhhF;
  const int tid = threadIdx.x, q = tid >> 6, l = tid & 63;
  const int l15 = l & 15, l4 = l >> 4;
  const int swz = (l15 & 7) << 3;
  const int rbase = l15 * 256;

  __shared__ __attribute__((aligned(16))) unsigned short hbuf[2][4096];

  short8 wf[4][8];
  #pragma unroll
  for (int ni = 0; ni < 4; ++ni){
    int n = 64*q + 16*ni + l15;
    #pragma unroll
    for (int ks = 0; ks < 8; ++ks)
      wf[ni][ks] = pack8(Whh + (size_t)n * HH + ks*32 + l4*8);
  }
  for (int i = tid; i < 2048; i += 256) ((unsigned*)hbuf[0])[i] = 0u;  // h_0 = 0

  const size_t strideS = 16384;   // ushorts per timestep
  const size_t laneOff = (size_t)bq*4096 + (size_t)q*1024 + (size_t)l*16;
  const unsigned short* xpP = xpF + (size_t)dir*TT*strideS + laneOff;
  unsigned short* hD = hF + (size_t)dir*TT*strideS + laneOff;

  uint4 xqA0, xqA1, xqB0, xqB1;
  { const uint4* p = (const uint4*)xpP;             xqA0 = p[0]; xqA1 = p[1]; }
  { const uint4* p = (const uint4*)(xpP + strideS); xqB0 = p[0]; xqB1 = p[1]; }

  // first deferred store targets this thread's own t0 slot with zeros;
  // overwritten later by the same thread -> benign, branch-free loop.
  uint4 p0 = {0,0,0,0}, p1 = {0,0,0,0};
  size_t prevOff = 0;
  barrier_lgkm();

  auto bstep = [&](int s, uint4& XQ0, uint4& XQ1,
                   const unsigned short* RD, unsigned short* WR){
    // long-latency LDS reads of h_{s-1} first
    short8 b[8];
    #pragma unroll
    for (int ks = 0; ks < 8; ++ks)
      b[ks] = *(const short8*)(RD + ((rbase + ks*32 + l4*8) ^ swz));
    // deferred global store of previous h (stays in flight across barriers)
    *(uint4*)(hD + prevOff)     = p0;
    *(uint4*)(hD + prevOff + 8) = p1;
    // unpack current xp into even accumulators
    f32x4 accE[4], accO[4];
    {
      unsigned W8[8] = {XQ0.x, XQ0.y, XQ0.z, XQ0.w, XQ1.x, XQ1.y, XQ1.z, XQ1.w};
      #pragma unroll
      for (int ni = 0; ni < 4; ++ni){
        accE[ni][0] = bfLO(W8[ni*2]);   accE[ni][1] = bfHI(W8[ni*2]);
        accE[ni][2] = bfLO(W8[ni*2+1]); accE[ni][3] = bfHI(W8[ni*2+1]);
        accO[ni][0] = 0.f; accO[ni][1] = 0.f; accO[ni][2] = 0.f; accO[ni][3] = 0.f;
      }
    }
    // prefetch xp for s+2 (first use is 2 steps away)
    {
      int sn = (s + 2 < TT) ? s + 2 : TT - 1;
      const uint4* src = (const uint4*)(xpP + (size_t)sn * strideS);
      XQ0 = src[0]; XQ1 = src[1];
    }
    // Whh * h^T: 8 independent chains of depth 4
    #pragma unroll
    for (int ks = 0; ks < 8; ks += 2){
      #pragma unroll
      for (int ni = 0; ni < 4; ++ni){
        accE[ni] = MFMA(wf[ni][ks],   b[ks],   accE[ni]);
        accO[ni] = MFMA(wf[ni][ks+1], b[ks+1], accO[ni]);
      }
    }
    // tanh + pack -> LDS write + stage for deferred global store
    unsigned wd[8];
    #pragma unroll
    for (int ni = 0; ni < 4; ++ni){
      float t0 = ftanh(accE[ni][0] + accO[ni][0]);
      float t1 = ftanh(accE[ni][1] + accO[ni][1]);
      float t2 = ftanh(accE[ni][2] + accO[ni][2]);
      float t3 = ftanh(accE[ni][3] + accO[ni][3]);
      unsigned lo = pack2(t0, t1), hi = pack2(t2, t3);
      wd[ni*2] = lo; wd[ni*2+1] = hi;
      int ea = rbase + ((64*q + 16*ni + 4*l4) ^ swz);
      uint2 v; v.x = lo; v.y = hi;
      *(uint2*)(WR + ea) = v;
    }
    p0.x=wd[0]; p0.y=wd[1]; p0.z=wd[2]; p0.w=wd[3];
    p1.x=wd[4]; p1.y=wd[5]; p1.z=wd[6]; p1.w=wd[7];
    prevOff = (size_t)(dir ? (TT - 1 - s) : s) * strideS;
    barrier_lgkm();
  };

  for (int s = 0; s < TT; s += 2){
    bstep(s,     xqA0, xqA1, hbuf[0], hbuf[1]);
    bstep(s + 1, xqB0, xqB1, hbuf[1], hbuf[0]);
  }
  *(uint4*)(hD + prevOff)     = p0;
  *(uint4*)(hD + prevOff + 8) = p1;
}

// ---------------------------------------------------------------------------
// Phase C: latent scan, 4 blocks (bq) x 256 thr (4 waves), 2 LDS-only
// barriers/step. hl/hr/eps prefetched 2 steps ahead (manual unroll-2).
// Wave q owns out-cols [16q,16q+16) of mu AND sig -> z fully in-register.
// ---------------------------------------------------------------------------
__global__ __launch_bounds__(256, 1) void phaseC(
    const float* __restrict__ Wt,  const float* __restrict__ bt,
    const float* __restrict__ Wmu, const float* __restrict__ bmu,
    const float* __restrict__ Wsig,const float* __restrict__ bsig,
    const float* __restrict__ eps, const unsigned short* __restrict__ hF,
    float* __restrict__ out)
{
  const int bq = blockIdx.x;
  const int tid = threadIdx.x, q = tid >> 6, l = tid & 63;
  const int l15 = l & 15, l4 = l >> 4;
  const int swz = (l15 & 7) << 3;
  const int rbase = l15 * 256;
  const int zrbase = l15 * 64;

  __shared__ __attribute__((aligned(16))) unsigned short zbuf[1024];   // 16 x 64
  __shared__ __attribute__((aligned(16))) unsigned short hbuf[4096];   // 16 x 256

  // transition: A-frags of Wt rows (out-cols of H), K = DZ = 64
  short8 wtf[4][2]; f32x4 btb[4];
  #pragma unroll
  for (int ni = 0; ni < 4; ++ni){
    int n = 64*q + 16*ni + l15;
    #pragma unroll
    for (int ks = 0; ks < 2; ++ks)
      wtf[ni][ks] = pack8(Wt + (size_t)n * DZZ + ks*32 + l4*8);
    float4 b4 = *(const float4*)(bt + 64*q + 16*ni + 4*l4);
    btb[ni][0]=b4.x; btb[ni][1]=b4.y; btb[ni][2]=b4.z; btb[ni][3]=b4.w;
  }
  // mu/sig: A-frags of Wmu/Wsig rows (this wave's 16 out-cols), K = H = 256
  short8 wm[8], wsg[8];
  {
    int r = 16*q + l15;
    #pragma unroll
    for (int ks = 0; ks < 8; ++ks){
      wm[ks]  = pack8(Wmu  + (size_t)r * HH + ks*32 + l4*8);
      wsg[ks] = pack8(Wsig + (size_t)r * HH + ks*32 + l4*8);
    }
  }
  f32x4 bm4, bs4;
  {
    float4 a = *(const float4*)(bmu  + 16*q + 4*l4);
    float4 b = *(const float4*)(bsig + 16*q + 4*l4);
    bm4[0]=a.x; bm4[1]=a.y; bm4[2]=a.z; bm4[3]=a.w;
    bs4[0]=b.x; bs4[1]=b.y; bs4[2]=b.z; bs4[3]=b.w;
  }
  for (int i = tid; i < 512; i += 256) ((unsigned*)zbuf)[i] = 0u;   // z_0 = 0

  const size_t strideS = 16384;
  const size_t laneOff = (size_t)bq*4096 + (size_t)q*1024 + (size_t)l*16;
  const unsigned short* hLp = hF + laneOff;
  const unsigned short* hRp = hLp + (size_t)TT * strideS;
  const float* eP = eps + ((size_t)(16*bq + l15)) * 64 + 16*q + 4*l4;  // + t*4096

  uint4 hlA0, hlA1, hrA0, hrA1, hlB0, hlB1, hrB0, hrB1;
  f32x4 efA, efB;
  {
    const uint4* sl = (const uint4*)hLp;              hlA0 = sl[0]; hlA1 = sl[1];
    const uint4* sr = (const uint4*)hRp;              hrA0 = sr[0]; hrA1 = sr[1];
    const uint4* tl = (const uint4*)(hLp + strideS);  hlB0 = tl[0]; hlB1 = tl[1];
    const uint4* tr = (const uint4*)(hRp + strideS);  hrB0 = tr[0]; hrB1 = tr[1];
    float4 e0 = *(const float4*)eP;
    float4 e1 = *(const float4*)(eP + 4096);
    efA[0]=e0.x; efA[1]=e0.y; efA[2]=e0.z; efA[3]=e0.w;
    efB[0]=e1.x; efB[1]=e1.y; efB[2]=e1.z; efB[3]=e1.w;
  }
  const size_t TBZ = (size_t)TT * 64 * 64;
  f32x4 dz = {0.f,0.f,0.f,0.f}, dmu = {0.f,0.f,0.f,0.f}, dsp = {0.f,0.f,0.f,0.f};
  // first deferred store hits this thread's own t=0 slot (disjoint per block)
  size_t obPrev = ((size_t)16*bq + l15)*64 + 16*q + 4*l4;
  barrier_lgkm();

  auto cstep = [&](int t, uint4& HL0, uint4& HL1, uint4& HR0, uint4& HR1, f32x4& EF){
    // z_prev reads first (critical path)
    short8 zb[2];
    #pragma unroll
    for (int ks = 0; ks < 2; ++ks)
      zb[ks] = *(const short8*)(zbuf + ((zrbase + ks*32 + l4*8) ^ swz));
    // deferred out stores for t-1 (stay in flight)
    *(float4*)(out + obPrev)         = *(float4*)&dz;
    *(float4*)(out + TBZ + obPrev)   = *(float4*)&dmu;
    *(float4*)(out + 2*TBZ + obPrev) = *(float4*)&dsp;
    // 1) transition: Wt * z_prev^T + bt (4 chains, depth 2)
    f32x4 at[4];
    #pragma unroll
    for (int ni = 0; ni < 4; ++ni) at[ni] = btb[ni];
    #pragma unroll
    for (int ks = 0; ks < 2; ++ks)
      #pragma unroll
      for (int ni = 0; ni < 4; ++ni)
        at[ni] = MFMA(wtf[ni][ks], zb[ks], at[ni]);
    // 2) h_t = (tanh + hl + hr)/3 -> swizzled LDS (b64)
    {
      unsigned HLw[8] = {HL0.x, HL0.y, HL0.z, HL0.w, HL1.x, HL1.y, HL1.z, HL1.w};
      unsigned HRw[8] = {HR0.x, HR0.y, HR0.z, HR0.w, HR1.x, HR1.y, HR1.z, HR1.w};
      #pragma unroll
      for (int ni = 0; ni < 4; ++ni){
        unsigned wl0 = HLw[ni*2], wl1 = HLw[ni*2+1];
        unsigned wr0 = HRw[ni*2], wr1 = HRw[ni*2+1];
        float h0 = (ftanh(at[ni][0]) + bfLO(wl0) + bfLO(wr0)) * (1.f/3.f);
        float h1 = (ftanh(at[ni][1]) + bfHI(wl0) + bfHI(wr0)) * (1.f/3.f);
        float h2 = (ftanh(at[ni][2]) + bfLO(wl1) + bfLO(wr1)) * (1.f/3.f);
        float h3 = (ftanh(at[ni][3]) + bfHI(wl1) + bfHI(wr1)) * (1.f/3.f);
        int ea = rbase + ((64*q + 16*ni + 4*l4) ^ swz);
        uint2 v; v.x = pack2(h0, h1); v.y = pack2(h2, h3);
        *(uint2*)(hbuf + ea) = v;
      }
    }
    // prefetch hl/hr for t+2 (consumed above; first use 2 steps away)
    {
      int tn = (t + 2 < TT) ? t + 2 : TT - 1;
      const uint4* sl = (const uint4*)(hLp + (size_t)tn*strideS);
      const uint4* sr = (const uint4*)(hRp + (size_t)tn*strideS);
      HL0 = sl[0]; HL1 = sl[1]; HR0 = sr[0]; HR1 = sr[1];
    }
    barrier_lgkm();   // B1: h_t visible

    // 3) mu/sig: 4 chains of depth 4
    short8 hbl[4];
    #pragma unroll
    for (int ks = 0; ks < 4; ++ks)
      hbl[ks] = *(const short8*)(hbuf + ((rbase + ks*32 + l4*8) ^ swz));
    f32x4 am0 = bm4, as0 = bs4;
    #pragma unroll
    for (int ks = 0; ks < 4; ++ks){
      am0 = MFMA(wm[ks],  hbl[ks], am0);
      as0 = MFMA(wsg[ks], hbl[ks], as0);
    }
    short8 hbh[4];
    #pragma unroll
    for (int ks = 0; ks < 4; ++ks)
      hbh[ks] = *(const short8*)(hbuf + ((rbase + (ks+4)*32 + l4*8) ^ swz));
    f32x4 am1 = {0.f,0.f,0.f,0.f}, as1 = {0.f,0.f,0.f,0.f};
    #pragma unroll
    for (int ks = 0; ks < 4; ++ks){
      am1 = MFMA(wm[ks+4],  hbh[ks], am1);
      as1 = MFMA(wsg[ks+4], hbh[ks], as1);
    }
    f32x4 mu = am0 + am1;
    f32x4 sg = as0 + as1;
    // 4) reparameterization in-register; z -> swizzled LDS (b64)
    #pragma unroll
    for (int reg = 0; reg < 4; ++reg){
      float sp = fsoftplus(sg[reg]);
      float zv = __builtin_fmaf(sp, EF[reg], mu[reg]);
      dz[reg] = zv; dmu[reg] = mu[reg]; dsp[reg] = sp;
    }
    {
      int zea = zrbase + ((16*q + 4*l4) ^ swz);
      uint2 v; v.x = pack2(dz[0], dz[1]); v.y = pack2(dz[2], dz[3]);
      *(uint2*)(zbuf + zea) = v;
    }
    // prefetch eps for t+2 (after consumption)
    {
      int tn = (t + 2 < TT) ? t + 2 : TT - 1;
      float4 e4 = *(const float4*)(eP + (size_t)tn*4096);
      EF[0]=e4.x; EF[1]=e4.y; EF[2]=e4.z; EF[3]=e4.w;
    }
    obPrev = ((size_t)t*64 + 16*bq + l15)*64 + 16*q + 4*l4;
    barrier_lgkm();   // B2: z_t visible
  };

  for (int t = 0; t < TT; t += 2){
    cstep(t,     hlA0, hlA1, hrA0, hrA1, efA);
    cstep(t + 1, hlB0, hlB1, hrB0, hrB1, efB);
  }
  *(float4*)(out + obPrev)         = *(float4*)&dz;
  *(float4*)(out + TBZ + obPrev)   = *(float4*)&dmu;
  *(float4*)(out + 2*TBZ + obPrev) = *(float4*)&dsp;
}

// ---------------------------------------------------------------------------
extern "C" void kernel_launch(void* const* d_in, const int* in_sizes, int n_in,
                              void* d_out, int out_size, void* d_ws, size_t ws_size,
                              hipStream_t stream)
{
  const float* X      = (const float*)d_in[0];
  const float* Wih_f  = (const float*)d_in[1];
  const float* Whh_f  = (const float*)d_in[2];
  const float* bih_f  = (const float*)d_in[3];
  const float* bhh_f  = (const float*)d_in[4];
  const float* Wih_b  = (const float*)d_in[5];
  const float* Whh_b  = (const float*)d_in[6];
  const float* bih_b  = (const float*)d_in[7];
  const float* bhh_b  = (const float*)d_in[8];
  const float* Wt     = (const float*)d_in[9];
  const float* bt     = (const float*)d_in[10];
  const float* Wmu    = (const float*)d_in[11];
  const float* bmu    = (const float*)d_in[12];
  const float* Wsig   = (const float*)d_in[13];
  const float* bsig   = (const float*)d_in[14];
  const float* eps    = (const float*)d_in[15];

  // Workspace: xpF (33.5MB) + hF (33.5MB)
  unsigned short* xpF = (unsigned short*)d_ws;
  unsigned short* hF  = xpF + (size_t)2 * TT * 16384;

  phaseA<<<dim3(1024), dim3(256), 0, stream>>>(X, Wih_f, bih_f, bhh_f, Wih_b, bih_b, bhh_b, xpF);
  phaseB<<<dim3(8), dim3(256), 0, stream>>>(Whh_f, Whh_b, xpF, hF);
  phaseC<<<dim3(4), dim3(256), 0, stream>>>(Wt, bt, Wmu, bmu, Wsig, bsig, eps, hF, (float*)d_out);
}

// Round 6
// 1132.077 us; speedup vs baseline: 1.1237x; 1.1013x over previous
//
#include <hip/hip_runtime.h>

// Problem dims
#define TT 512
#define BB 64
#define DXX 128
#define HH 256
#define DZZ 64

typedef __attribute__((ext_vector_type(8))) short short8;
typedef __attribute__((ext_vector_type(4))) float f32x4;

#define DEV static __device__ __forceinline__
#define MFMA(a,b,c) __builtin_amdgcn_mfma_f32_16x16x32_bf16((a),(b),(c),0,0,0)

DEV unsigned short f2bf(float f){
  unsigned u = __builtin_bit_cast(unsigned, f);
  u += 0x7FFFu + ((u >> 16) & 1u);          // RNE
  return (unsigned short)(u >> 16);
}
DEV unsigned pack2(float lo, float hi){     // 2 f32 -> packed bf16x2
  return (unsigned)f2bf(lo) | ((unsigned)f2bf(hi) << 16);
}
DEV float bfLO(unsigned u){ return __builtin_bit_cast(float, u << 16); }
DEV float bfHI(unsigned u){ return __builtin_bit_cast(float, u & 0xffff0000u); }
DEV float ftanh(float x){
  float a = fabsf(x);
  float e = __expf(-2.f * a);
  float r = __builtin_amdgcn_rcpf(1.f + e);
  float t = (1.f - e) * r;
  return copysignf(t, x);
}
DEV float fsoftplus(float x){
  float e = __expf(fminf(x, 20.f));
  float s = __logf(1.f + e);
  return (x > 20.f) ? x : s;
}
// LDS-visibility barrier as ONE raw asm: the compiler cannot attach a
// vmcnt(0) drain to it (T4), and no sched_barrier fences (m141 lesson).
DEV void barrier_l(){
  asm volatile("s_waitcnt lgkmcnt(0)\n\ts_barrier" ::: "memory");
}

// Fragment conventions (verified rounds 1-5, mfma_f32_16x16x32_bf16), swapped:
//   D = A*B, A = weight tile (16 out-cols x K), B = state^T (K x 16 batch).
//   A-frag: lane l elem e: W[outcol = l&15][k = (l>>4)*8 + e]
//   B-frag: lane l elem e: h[batch = l&15][k = (l>>4)*8 + e]
//   C/D:    lane l reg r:  value(batch = l&15, outcol = tile + 4*(l>>4) + r)

// ---------------------------------------------------------------------------
// Phase A: xp = X @ Wih^T + bih + bhh (both dirs), bf16 lane-packed:
// xpF[d][s][bq][q][l][16]
// ---------------------------------------------------------------------------
__global__ __launch_bounds__(256, 2) void phaseA(
    const float* __restrict__ X,
    const float* __restrict__ WihF, const float* __restrict__ bihF, const float* __restrict__ bhhF,
    const float* __restrict__ WihB, const float* __restrict__ bihB, const float* __restrict__ bhhB,
    unsigned short* __restrict__ xpF)
{
  const int bid = blockIdx.x;
  const int d = bid >> 9, s = bid & 511;
  const int ts = d ? (TT - 1 - s) : s;
  const float* W  = d ? WihB : WihF;
  const float* bi = d ? bihB : bihF;
  const float* bh = d ? bhhB : bhhF;

  const int tid = threadIdx.x, q = tid >> 6, l = tid & 63;
  const int l15 = l & 15, l4 = l >> 4;

  short8 wf[4][4];
  f32x4 bias[4];
  #pragma unroll
  for (int ni = 0; ni < 4; ++ni){
    int n = 64*q + 16*ni + l15;
    #pragma unroll
    for (int ks = 0; ks < 4; ++ks){
      const float* p = W + (size_t)n * DXX + ks*32 + l4*8;
      short8 v;
      #pragma unroll
      for (int i = 0; i < 8; ++i) v[i] = (short)f2bf(p[i]);
      wf[ni][ks] = v;
    }
    int n0 = 64*q + 16*ni + 4*l4;
    float4 b1 = *(const float4*)(bi + n0);
    float4 b2 = *(const float4*)(bh + n0);
    bias[ni][0]=b1.x+b2.x; bias[ni][1]=b1.y+b2.y; bias[ni][2]=b1.z+b2.z; bias[ni][3]=b1.w+b2.w;
  }

  #pragma unroll
  for (int bq = 0; bq < 4; ++bq){
    const float* xr = X + ((size_t)ts * 64 + 16*bq + l15) * DXX;
    short8 xf[4];
    #pragma unroll
    for (int ks = 0; ks < 4; ++ks){
      const float* p = xr + ks*32 + l4*8;
      short8 v;
      #pragma unroll
      for (int i = 0; i < 8; ++i) v[i] = (short)f2bf(p[i]);
      xf[ks] = v;
    }

    f32x4 acc[4];
    #pragma unroll
    for (int ni = 0; ni < 4; ++ni) acc[ni] = MFMA(wf[ni][0], xf[0], bias[ni]);
    #pragma unroll
    for (int ks = 1; ks < 4; ++ks)
      #pragma unroll
      for (int ni = 0; ni < 4; ++ni)
        acc[ni] = MFMA(wf[ni][ks], xf[ks], acc[ni]);

    unsigned wd[8];
    #pragma unroll
    for (int ni = 0; ni < 4; ++ni){
      wd[ni*2]   = pack2(acc[ni][0], acc[ni][1]);
      wd[ni*2+1] = pack2(acc[ni][2], acc[ni][3]);
    }
    unsigned short* dst = xpF + ((((size_t)d*TT + s)*4 + bq)*4 + q)*1024 + (size_t)l*16;
    uint4 o0 = {wd[0], wd[1], wd[2], wd[3]};
    uint4 o1 = {wd[4], wd[5], wd[6], wd[7]};
    ((uint4*)dst)[0] = o0;
    ((uint4*)dst)[1] = o1;
  }
}

// ---------------------------------------------------------------------------
// Phase B: two RNN scans, 8 blocks (dir,bq) x 256 thr (4 waves).
// Whh in regs; h in double-buffered swizzled LDS; 1 raw barrier/step;
// xp prefetched 2 steps ahead; h stored to global at END of step (after the
// prefetch loads -> stores never gate a load-use vmcnt wait).
// ---------------------------------------------------------------------------
__global__ __launch_bounds__(256, 1) void phaseB(
    const float* __restrict__ WhhF, const float* __restrict__ WhhB,
    const unsigned short* __restrict__ xpF, unsigned short* __restrict__ hF)
{
  const int dir = blockIdx.x >> 2, bq = blockIdx.x & 3;
  const float* Whh = dir ? WhhB : WhhF;
  const int tid = threadIdx.x, q = tid >> 6, l = tid & 63;
  const int l15 = l & 15, l4 = l >> 4;
  const int swz = (l15 & 7) << 3;
  const int rbase = l15 * 256;

  __shared__ __attribute__((aligned(16))) unsigned short hbuf[2][4096];

  short8 wf[4][8];
  #pragma unroll
  for (int ni = 0; ni < 4; ++ni){
    int n = 64*q + 16*ni + l15;
    #pragma unroll
    for (int ks = 0; ks < 8; ++ks){
      const float* p = Whh + (size_t)n * HH + ks*32 + l4*8;
      short8 v;
      #pragma unroll
      for (int i = 0; i < 8; ++i) v[i] = (short)f2bf(p[i]);
      wf[ni][ks] = v;
    }
  }
  for (int i = tid; i < 2048; i += 256) ((unsigned*)hbuf[0])[i] = 0u;  // h_0 = 0

  const size_t strideS = 16384;   // ushorts per timestep
  const size_t laneOff = (size_t)bq*4096 + (size_t)q*1024 + (size_t)l*16;
  const unsigned short* xpP = xpF + (size_t)dir*TT*strideS + laneOff;
  unsigned short* hD = hF + (size_t)dir*TT*strideS + laneOff;

  uint4 xqA0, xqA1, xqB0, xqB1;
  { const uint4* p = (const uint4*)xpP;             xqA0 = p[0]; xqA1 = p[1]; }
  { const uint4* p = (const uint4*)(xpP + strideS); xqB0 = p[0]; xqB1 = p[1]; }

  barrier_l();

  auto bstep = [&](int s, uint4& XQ0, uint4& XQ1,
                   const unsigned short* RD, unsigned short* WR){
    // 1) LDS reads of h_{s-1} first (longest latency on the chain)
    short8 b[8];
    #pragma unroll
    for (int ks = 0; ks < 8; ++ks)
      b[ks] = *(const short8*)(RD + ((rbase + ks*32 + l4*8) ^ swz));
    // 2) acc <- xp (loaded 2 steps ago; stores are newer in FIFO -> no gating)
    f32x4 accE[4], accO[4];
    {
      unsigned W8[8] = {XQ0.x, XQ0.y, XQ0.z, XQ0.w, XQ1.x, XQ1.y, XQ1.z, XQ1.w};
      #pragma unroll
      for (int ni = 0; ni < 4; ++ni){
        accE[ni][0] = bfLO(W8[ni*2]);   accE[ni][1] = bfHI(W8[ni*2]);
        accE[ni][2] = bfLO(W8[ni*2+1]); accE[ni][3] = bfHI(W8[ni*2+1]);
        accO[ni][0] = 0.f; accO[ni][1] = 0.f; accO[ni][2] = 0.f; accO[ni][3] = 0.f;
      }
    }
    // 3) prefetch xp for s+2
    {
      int sn = (s + 2 < TT) ? s + 2 : TT - 1;
      const uint4* src = (const uint4*)(xpP + (size_t)sn * strideS);
      XQ0 = src[0]; XQ1 = src[1];
    }
    // 4) Whh * h^T : 8 independent chains of depth 4
    #pragma unroll
    for (int ks = 0; ks < 8; ks += 2){
      #pragma unroll
      for (int ni = 0; ni < 4; ++ni){
        accE[ni] = MFMA(wf[ni][ks],   b[ks],   accE[ni]);
        accO[ni] = MFMA(wf[ni][ks+1], b[ks+1], accO[ni]);
      }
    }
    // 5) tanh + pack -> LDS write; 6) global store of h_s (AFTER the loads)
    unsigned wd[8];
    #pragma unroll
    for (int ni = 0; ni < 4; ++ni){
      float t0 = ftanh(accE[ni][0] + accO[ni][0]);
      float t1 = ftanh(accE[ni][1] + accO[ni][1]);
      float t2 = ftanh(accE[ni][2] + accO[ni][2]);
      float t3 = ftanh(accE[ni][3] + accO[ni][3]);
      unsigned lo = pack2(t0, t1), hi = pack2(t2, t3);
      wd[ni*2] = lo; wd[ni*2+1] = hi;
      int ea = rbase + ((64*q + 16*ni + 4*l4) ^ swz);
      uint2 v; v.x = lo; v.y = hi;
      *(uint2*)(WR + ea) = v;
    }
    {
      size_t off = (size_t)(dir ? (TT - 1 - s) : s) * strideS;
      uint4 o0 = {wd[0], wd[1], wd[2], wd[3]};
      uint4 o1 = {wd[4], wd[5], wd[6], wd[7]};
      *(uint4*)(hD + off)     = o0;
      *(uint4*)(hD + off + 8) = o1;
    }
    barrier_l();
  };

  for (int s = 0; s < TT; s += 2){
    bstep(s,     xqA0, xqA1, hbuf[0], hbuf[1]);
    bstep(s + 1, xqB0, xqB1, hbuf[1], hbuf[0]);
  }
}

// ---------------------------------------------------------------------------
// Phase C: latent scan, 4 blocks (bq) x 256 thr (4 waves), 2 raw barriers.
// Wave q owns out-cols [16q,16q+16) of mu AND sig -> z fully in-register.
// Outputs stored at END of step, after all loads (FIFO decoupling).
// ---------------------------------------------------------------------------
__global__ __launch_bounds__(256, 1) void phaseC(
    const float* __restrict__ Wt,  const float* __restrict__ bt,
    const float* __restrict__ Wmu, const float* __restrict__ bmu,
    const float* __restrict__ Wsig,const float* __restrict__ bsig,
    const float* __restrict__ eps, const unsigned short* __restrict__ hF,
    float* __restrict__ out)
{
  const int bq = blockIdx.x;
  const int tid = threadIdx.x, q = tid >> 6, l = tid & 63;
  const int l15 = l & 15, l4 = l >> 4;
  const int swz = (l15 & 7) << 3;
  const int rbase = l15 * 256;
  const int zrbase = l15 * 64;

  __shared__ __attribute__((aligned(16))) unsigned short zbuf[1024];   // 16 x 64
  __shared__ __attribute__((aligned(16))) unsigned short hbuf[4096];   // 16 x 256

  // transition: A-frags of Wt rows (out-cols of H), K = DZ = 64
  short8 wtf[4][2]; f32x4 btb[4];
  #pragma unroll
  for (int ni = 0; ni < 4; ++ni){
    int n = 64*q + 16*ni + l15;
    #pragma unroll
    for (int ks = 0; ks < 2; ++ks){
      const float* p = Wt + (size_t)n * DZZ + ks*32 + l4*8;
      short8 v;
      #pragma unroll
      for (int i = 0; i < 8; ++i) v[i] = (short)f2bf(p[i]);
      wtf[ni][ks] = v;
    }
    float4 b4 = *(const float4*)(bt + 64*q + 16*ni + 4*l4);
    btb[ni][0]=b4.x; btb[ni][1]=b4.y; btb[ni][2]=b4.z; btb[ni][3]=b4.w;
  }
  // mu/sig: A-frags of Wmu/Wsig rows (this wave's 16 out-cols), K = H = 256
  short8 wm[8], wsg[8];
  {
    int r = 16*q + l15;
    #pragma unroll
    for (int ks = 0; ks < 8; ++ks){
      const float* pm = Wmu  + (size_t)r * HH + ks*32 + l4*8;
      const float* ps = Wsig + (size_t)r * HH + ks*32 + l4*8;
      short8 vm, vs;
      #pragma unroll
      for (int i = 0; i < 8; ++i){ vm[i] = (short)f2bf(pm[i]); vs[i] = (short)f2bf(ps[i]); }
      wm[ks] = vm; wsg[ks] = vs;
    }
  }
  f32x4 bm4, bs4;
  {
    float4 a = *(const float4*)(bmu  + 16*q + 4*l4);
    float4 b = *(const float4*)(bsig + 16*q + 4*l4);
    bm4[0]=a.x; bm4[1]=a.y; bm4[2]=a.z; bm4[3]=a.w;
    bs4[0]=b.x; bs4[1]=b.y; bs4[2]=b.z; bs4[3]=b.w;
  }
  for (int i = tid; i < 512; i += 256) ((unsigned*)zbuf)[i] = 0u;   // z_0 = 0

  const size_t strideS = 16384;
  const size_t laneOff = (size_t)bq*4096 + (size_t)q*1024 + (size_t)l*16;
  const unsigned short* hLp = hF + laneOff;
  const unsigned short* hRp = hLp + (size_t)TT * strideS;
  const float* eP = eps + ((size_t)(16*bq + l15)) * 64 + 16*q + 4*l4;  // + t*4096

  uint4 hlA0, hlA1, hrA0, hrA1, hlB0, hlB1, hrB0, hrB1;
  f32x4 efA, efB;
  {
    const uint4* sl = (const uint4*)hLp;              hlA0 = sl[0]; hlA1 = sl[1];
    const uint4* sr = (const uint4*)hRp;              hrA0 = sr[0]; hrA1 = sr[1];
    const uint4* tl = (const uint4*)(hLp + strideS);  hlB0 = tl[0]; hlB1 = tl[1];
    const uint4* tr = (const uint4*)(hRp + strideS);  hrB0 = tr[0]; hrB1 = tr[1];
    float4 e0 = *(const float4*)eP;
    float4 e1 = *(const float4*)(eP + 4096);
    efA[0]=e0.x; efA[1]=e0.y; efA[2]=e0.z; efA[3]=e0.w;
    efB[0]=e1.x; efB[1]=e1.y; efB[2]=e1.z; efB[3]=e1.w;
  }
  const size_t TBZ = (size_t)TT * 64 * 64;
  const f32x4 zero4 = {0.f, 0.f, 0.f, 0.f};
  barrier_l();

  auto cstep = [&](int t, uint4& HL0, uint4& HL1, uint4& HR0, uint4& HR1, f32x4& EF){
    // 1) z_prev reads first (critical path)
    short8 zb0 = *(const short8*)(zbuf + ((zrbase +  0 + l4*8) ^ swz));
    short8 zb1 = *(const short8*)(zbuf + ((zrbase + 32 + l4*8) ^ swz));
    // 2) transition: Wt * z_prev^T + bt (C-init directly from btb, no copies)
    f32x4 at[4];
    #pragma unroll
    for (int ni = 0; ni < 4; ++ni) at[ni] = MFMA(wtf[ni][0], zb0, btb[ni]);
    #pragma unroll
    for (int ni = 0; ni < 4; ++ni) at[ni] = MFMA(wtf[ni][1], zb1, at[ni]);
    // 3) h_t = (tanh + hl + hr)/3 -> swizzled LDS (hl/hr loaded 2 steps ago)
    {
      unsigned HLw[8] = {HL0.x, HL0.y, HL0.z, HL0.w, HL1.x, HL1.y, HL1.z, HL1.w};
      unsigned HRw[8] = {HR0.x, HR0.y, HR0.z, HR0.w, HR1.x, HR1.y, HR1.z, HR1.w};
      #pragma unroll
      for (int ni = 0; ni < 4; ++ni){
        unsigned wl0 = HLw[ni*2], wl1 = HLw[ni*2+1];
        unsigned wr0 = HRw[ni*2], wr1 = HRw[ni*2+1];
        float h0 = (ftanh(at[ni][0]) + bfLO(wl0) + bfLO(wr0)) * (1.f/3.f);
        float h1 = (ftanh(at[ni][1]) + bfHI(wl0) + bfHI(wr0)) * (1.f/3.f);
        float h2 = (ftanh(at[ni][2]) + bfLO(wl1) + bfLO(wr1)) * (1.f/3.f);
        float h3 = (ftanh(at[ni][3]) + bfHI(wl1) + bfHI(wr1)) * (1.f/3.f);
        int ea = rbase + ((64*q + 16*ni + 4*l4) ^ swz);
        uint2 v; v.x = pack2(h0, h1); v.y = pack2(h2, h3);
        *(uint2*)(hbuf + ea) = v;
      }
    }
    // 4) prefetch hl/hr for t+2 (loads precede this step's stores)
    {
      int tn = (t + 2 < TT) ? t + 2 : TT - 1;
      const uint4* sl = (const uint4*)(hLp + (size_t)tn*strideS);
      const uint4* sr = (const uint4*)(hRp + (size_t)tn*strideS);
      HL0 = sl[0]; HL1 = sl[1]; HR0 = sr[0]; HR1 = sr[1];
    }
    barrier_l();   // B1: h_t visible

    // 5) mu/sig: batch all 8 LDS reads, then 4 chains of depth 4
    short8 hb[8];
    #pragma unroll
    for (int ks = 0; ks < 8; ++ks)
      hb[ks] = *(const short8*)(hbuf + ((rbase + ks*32 + l4*8) ^ swz));
    f32x4 am0 = MFMA(wm[0],  hb[0], bm4);
    f32x4 as0 = MFMA(wsg[0], hb[0], bs4);
    f32x4 am1 = MFMA(wm[4],  hb[4], zero4);
    f32x4 as1 = MFMA(wsg[4], hb[4], zero4);
    #pragma unroll
    for (int ks = 1; ks < 4; ++ks){
      am0 = MFMA(wm[ks],    hb[ks],   am0);
      as0 = MFMA(wsg[ks],   hb[ks],   as0);
      am1 = MFMA(wm[ks+4],  hb[ks+4], am1);
      as1 = MFMA(wsg[ks+4], hb[ks+4], as1);
    }
    f32x4 mu = am0 + am1;
    f32x4 sg = as0 + as1;
    // 6) reparameterization; z -> swizzled LDS
    f32x4 dz, dsp;
    #pragma unroll
    for (int reg = 0; reg < 4; ++reg){
      float sp = fsoftplus(sg[reg]);
      dz[reg] = __builtin_fmaf(sp, EF[reg], mu[reg]);
      dsp[reg] = sp;
    }
    {
      int zea = zrbase + ((16*q + 4*l4) ^ swz);
      uint2 v; v.x = pack2(dz[0], dz[1]); v.y = pack2(dz[2], dz[3]);
      *(uint2*)(zbuf + zea) = v;
    }
    // 7) eps prefetch for t+2, then 8) output stores (AFTER all loads)
    {
      int tn = (t + 2 < TT) ? t + 2 : TT - 1;
      float4 e4 = *(const float4*)(eP + (size_t)tn*4096);
      EF[0]=e4.x; EF[1]=e4.y; EF[2]=e4.z; EF[3]=e4.w;
    }
    {
      size_t ob = ((size_t)t*64 + 16*bq + l15)*64 + 16*q + 4*l4;
      *(float4*)(out + ob)         = *(float4*)&dz;
      *(float4*)(out + TBZ + ob)   = *(float4*)&mu;
      *(float4*)(out + 2*TBZ + ob) = *(float4*)&dsp;
    }
    barrier_l();   // B2: z_t visible
  };

  for (int t = 0; t < TT; t += 2){
    cstep(t,     hlA0, hlA1, hrA0, hrA1, efA);
    cstep(t + 1, hlB0, hlB1, hrB0, hrB1, efB);
  }
}

// ---------------------------------------------------------------------------
extern "C" void kernel_launch(void* const* d_in, const int* in_sizes, int n_in,
                              void* d_out, int out_size, void* d_ws, size_t ws_size,
                              hipStream_t stream)
{
  const float* X      = (const float*)d_in[0];
  const float* Wih_f  = (const float*)d_in[1];
  const float* Whh_f  = (const float*)d_in[2];
  const float* bih_f  = (const float*)d_in[3];
  const float* bhh_f  = (const float*)d_in[4];
  const float* Wih_b  = (const float*)d_in[5];
  const float* Whh_b  = (const float*)d_in[6];
  const float* bih_b  = (const float*)d_in[7];
  const float* bhh_b  = (const float*)d_in[8];
  const float* Wt     = (const float*)d_in[9];
  const float* bt     = (const float*)d_in[10];
  const float* Wmu    = (const float*)d_in[11];
  const float* bmu    = (const float*)d_in[12];
  const float* Wsig   = (const float*)d_in[13];
  const float* bsig   = (const float*)d_in[14];
  const float* eps    = (const float*)d_in[15];

  // Workspace: xpF (33.5MB) + hF (33.5MB)
  unsigned short* xpF = (unsigned short*)d_ws;
  unsigned short* hF  = xpF + (size_t)2 * TT * 16384;

  phaseA<<<dim3(1024), dim3(256), 0, stream>>>(X, Wih_f, bih_f, bhh_f, Wih_b, bih_b, bhh_b, xpF);
  phaseB<<<dim3(8), dim3(256), 0, stream>>>(Whh_f, Whh_b, xpF, hF);
  phaseC<<<dim3(4), dim3(256), 0, stream>>>(Wt, bt, Wmu, bmu, Wsig, bsig, eps, hF, (float*)d_out);
}